// Round 1
// baseline (888.713 us; speedup 1.0000x reference)
//
#include <hip/hip_runtime.h>
#include <math.h>

#define BATCH 64
#define T 256
#define NF 64
#define H 128
#define H4 512                    // 4*H
#define HP1 129
#define WF_STRIDE (HP1 * H4)      // 66048 floats per feature
#define FEATS (NF * H + H)        // 8320
#define NTHREADS 512

__device__ __forceinline__ float sigmoidf_(float x) {
    return 1.0f / (1.0f + __expf(-x));
}

__device__ __forceinline__ float tanhf_(float x) {
    float ax = fabsf(x);
    float e = __expf(2.0f * ax);              // inf for large ax -> r = 1
    float r = 1.0f - 2.0f / (e + 1.0f);
    return copysignf(r, x);
}

__global__ __launch_bounds__(NTHREADS)
void lstm_scan_kernel(const float* __restrict__ X,
                      const int* __restrict__ lengths,
                      const float* __restrict__ W_lin,
                      const float* __restrict__ b_lin,
                      const float* __restrict__ W_dec,
                      const float* __restrict__ b_dec,
                      const float* __restrict__ W_out,
                      const float* __restrict__ b_out,
                      float* __restrict__ out)
{
    // feats layout: [0,H) = c_t, [H, H + NF*H) = h_t (f*H + h) -> contiguous
    // final-feature vector, matching concat([c_t, h_t.reshape(-1)]).
    __shared__ float s_feats[FEATS];          // 33280 B
    __shared__ float s_inp[H];                // decayed hidden row (K-vector)
    __shared__ float s_part[4][H4];           // K-split matvec partials, 8 KB
    __shared__ float s_X[4 * T];              // this sample's X block, 4 KB
    __shared__ float s_wdec[NF];
    __shared__ float s_bdec[NF];
    __shared__ float s_red[16];

    float* s_ct = s_feats;
    float* s_ht = s_feats + H;

    const int tid = threadIdx.x;
    const int b   = blockIdx.x;
    const int g4  = tid & 127;                // gate quad: gates [4*g4, 4*g4+4)
    const int kq  = tid >> 7;                 // K quarter: h in [32*kq, 32*kq+32)

    const float* Xb = X + b * 4 * T;
    const int len = lengths[b];

    // ---- init: zero h_t, stage X block + decay params into LDS ----
    for (int i = tid; i < NF * H; i += NTHREADS) s_ht[i] = 0.0f;
    for (int i = tid; i < 4 * T; i += NTHREADS) s_X[i] = Xb[i];
    if (tid < NF) {
        s_wdec[tid] = W_dec[tid];
        s_bdec[tid] = b_dec[tid];
    }
    __syncthreads();

    float c_t = 0.0f, acc = 0.0f, cnt = 0.0f;   // live in threads 0..127

    for (int j = 0; j < len; ++j) {
        // ---- uniform per-step scalars (LDS broadcast reads) ----
        const int   mj = (int)s_X[T + j];
        const float xj = s_X[2 * T + j];
        const float* Wf = W_lin + mj * WF_STRIDE;

        float bl0, bl1, bl2, bl3;
        if (tid < H) {
            const float dj    = s_X[3 * T + j];
            const float dm    = fmaf(s_wdec[mj], dj, s_bdec[mj]);
            const float decay = __expf(-fmaxf(0.0f, dm));
            s_inp[tid] = decay * s_ht[mj * H + tid];
            // prefetch bias row (depends only on mj; consumed after matvec)
            const int m4 = mj * H4;
            bl0 = b_lin[m4 + tid];
            bl1 = b_lin[m4 + H + tid];
            bl2 = b_lin[m4 + 2 * H + tid];
            bl3 = b_lin[m4 + 3 * H + tid];
        }
        __syncthreads();   // A: s_inp ready

        // ---- matvec partial: gates[4*g4+c] over K-quarter kq ----
        float4 a4 = make_float4(0.0f, 0.0f, 0.0f, 0.0f);
        {
            const float*  wr  = Wf + (1 + kq * 32) * H4 + 4 * g4;
            const float4* ivp = (const float4*)(s_inp + kq * 32);
            #pragma unroll
            for (int c = 0; c < 8; ++c) {
                const float4 v = ivp[c];
                const float* wrc = wr + (4 * c) * H4;
                const float4 w0 = *(const float4*)(wrc);
                const float4 w1 = *(const float4*)(wrc + H4);
                const float4 w2 = *(const float4*)(wrc + 2 * H4);
                const float4 w3 = *(const float4*)(wrc + 3 * H4);
                a4.x = fmaf(v.x, w0.x, a4.x); a4.y = fmaf(v.x, w0.y, a4.y);
                a4.z = fmaf(v.x, w0.z, a4.z); a4.w = fmaf(v.x, w0.w, a4.w);
                a4.x = fmaf(v.y, w1.x, a4.x); a4.y = fmaf(v.y, w1.y, a4.y);
                a4.z = fmaf(v.y, w1.z, a4.z); a4.w = fmaf(v.y, w1.w, a4.w);
                a4.x = fmaf(v.z, w2.x, a4.x); a4.y = fmaf(v.z, w2.y, a4.y);
                a4.z = fmaf(v.z, w2.z, a4.z); a4.w = fmaf(v.z, w2.w, a4.w);
                a4.x = fmaf(v.w, w3.x, a4.x); a4.y = fmaf(v.w, w3.y, a4.y);
                a4.z = fmaf(v.w, w3.z, a4.z); a4.w = fmaf(v.w, w3.w, a4.w);
            }
        }
        if (kq == 0) {   // x-term: row 0 of W_lin[mj]  (kq is wave-uniform)
            const float4 w = *(const float4*)(Wf + 4 * g4);
            a4.x = fmaf(xj, w.x, a4.x); a4.y = fmaf(xj, w.y, a4.y);
            a4.z = fmaf(xj, w.z, a4.z); a4.w = fmaf(xj, w.w, a4.w);
        }
        *(float4*)(&s_part[kq][4 * g4]) = a4;
        __syncthreads();   // B: partials ready

        // ---- gate nonlinearity + state update (threads 0..127 = h index) ----
        if (tid < H) {
            const int h = tid;
            const float gi = s_part[0][h]          + s_part[1][h]          + s_part[2][h]          + s_part[3][h]          + bl0;
            const float gf = s_part[0][H + h]      + s_part[1][H + h]      + s_part[2][H + h]      + s_part[3][H + h]      + bl1;
            const float go = s_part[0][2 * H + h]  + s_part[1][2 * H + h]  + s_part[2][2 * H + h]  + s_part[3][2 * H + h]  + bl2;
            const float gc = s_part[0][3 * H + h]  + s_part[1][3 * H + h]  + s_part[2][3 * H + h]  + s_part[3][3 * H + h]  + bl3;

            const float c_cand = sigmoidf_(gf) * c_t + sigmoidf_(gi) * tanhf_(gc);
            const float h_row  = sigmoidf_(go) * tanhf_(c_cand);
            s_ht[mj * H + h] = h_row;     // valid is always true for j < len
            acc += c_cand;
            cnt += 1.0f;

            const float tj = s_X[j];
            const float tn = (j < T - 1) ? s_X[j + 1] : (tj + 1.0f);
            const bool boundary = (j == len - 1) || (tn != tj);
            if (boundary) {
                c_t = acc / fmaxf(cnt, 1.0f);
                acc = 0.0f;
                cnt = 0.0f;
            }
        }
        __syncthreads();   // C: h_t updated, s_part free for next step
    }

    // ---- epilogue: z = feats @ W_out + b_out; softmax over 2 classes ----
    if (tid < H) s_ct[tid] = c_t;
    __syncthreads();

    float z0 = 0.0f, z1 = 0.0f;
    for (int i = tid; i < FEATS; i += NTHREADS) {
        const float f = s_feats[i];
        const float2 w = *(const float2*)(W_out + 2 * i);
        z0 = fmaf(f, w.x, z0);
        z1 = fmaf(f, w.y, z1);
    }
    #pragma unroll
    for (int off = 32; off > 0; off >>= 1) {
        z0 += __shfl_down(z0, off, 64);
        z1 += __shfl_down(z1, off, 64);
    }
    const int wave = tid >> 6, lane = tid & 63;
    if (lane == 0) { s_red[2 * wave] = z0; s_red[2 * wave + 1] = z1; }
    __syncthreads();
    if (tid == 0) {
        float a0 = b_out[0], a1 = b_out[1];
        #pragma unroll
        for (int w = 0; w < 8; ++w) { a0 += s_red[2 * w]; a1 += s_red[2 * w + 1]; }
        const float mx = fmaxf(a0, a1);
        const float e0 = __expf(a0 - mx), e1 = __expf(a1 - mx);
        const float inv = 1.0f / (e0 + e1);
        out[2 * b]     = e0 * inv;
        out[2 * b + 1] = e1 * inv;
    }
}

extern "C" void kernel_launch(void* const* d_in, const int* in_sizes, int n_in,
                              void* d_out, int out_size, void* d_ws, size_t ws_size,
                              hipStream_t stream) {
    const float* X      = (const float*)d_in[0];
    const int*   lens   = (const int*)d_in[1];
    const float* W_lin  = (const float*)d_in[2];
    const float* b_lin  = (const float*)d_in[3];
    const float* W_dec  = (const float*)d_in[4];
    const float* b_dec  = (const float*)d_in[5];
    const float* W_out  = (const float*)d_in[6];
    const float* b_out  = (const float*)d_in[7];
    float* out = (float*)d_out;

    hipLaunchKernelGGL(lstm_scan_kernel, dim3(BATCH), dim3(NTHREADS), 0, stream,
                       X, lens, W_lin, b_lin, W_dec, b_dec, W_out, b_out, out);
}

// Round 2
// 526.652 us; speedup vs baseline: 1.6875x; 1.6875x over previous
//
#include <hip/hip_runtime.h>
#include <math.h>

#define BATCH 64
#define T 256
#define NF 64
#define H 128
#define H4 512                    // 4*H
#define HP1 129
#define WF_STRIDE (HP1 * H4)      // 66048 floats per feature
#define FEATS (NF * H + H)        // 8320
#define NTHREADS 512
#define PACK_UINT4_PER_F 8192     // 16 i * 512 tid
#define PACK_BYTES (64u * PACK_UINT4_PER_F * 16u)   // 8 MB

typedef _Float16 half2_t __attribute__((ext_vector_type(2)));

__device__ __forceinline__ float sigmoidf_(float x) {
    return 1.0f / (1.0f + __expf(-x));
}

__device__ __forceinline__ float tanhf_(float x) {
    float ax = fabsf(x);
    float e = __expf(2.0f * ax);              // inf for large ax -> r = 1
    float r = 1.0f - 2.0f / (e + 1.0f);
    return copysignf(r, x);
}

__device__ __forceinline__ float fdot2_(half2_t a, half2_t b, float c) {
#if defined(__has_builtin)
#if __has_builtin(__builtin_amdgcn_fdot2)
    return __builtin_amdgcn_fdot2(a, b, c, false);
#else
    return fmaf((float)a.x, (float)b.x, fmaf((float)a.y, (float)b.y, c));
#endif
#else
    return fmaf((float)a.x, (float)b.x, fmaf((float)a.y, (float)b.y, c));
#endif
}

// ---------------- repack: W_lin rows 1..128 (h-part) -> fp16 blocked layout ----
// pack[(f*16 + i)*512 + tid] = uint4 of 4 half2:
//   for g in 0..3: ( W[f][1+k0][4*g4+g], W[f][2+k0][4*g4+g] )
//   where kq = tid>>7, g4 = tid&127, k0 = kq*32 + 2*i
__global__ __launch_bounds__(256)
void repack_kernel(const float* __restrict__ W_lin, uint4* __restrict__ pack) {
    const int lin = blockIdx.x * 256 + threadIdx.x;      // 0..524287
    const int f   = lin >> 13;
    const int i   = (lin >> 9) & 15;
    const int tid = lin & 511;
    const int kq  = tid >> 7;
    const int g4  = tid & 127;
    const int k0  = kq * 32 + 2 * i;
    const float* src = W_lin + (size_t)f * WF_STRIDE + (size_t)(1 + k0) * H4 + 4 * g4;
    const float4 r0 = *(const float4*)(src);
    const float4 r1 = *(const float4*)(src + H4);
    half2_t h[4];
    h[0].x = (_Float16)r0.x; h[0].y = (_Float16)r1.x;
    h[1].x = (_Float16)r0.y; h[1].y = (_Float16)r1.y;
    h[2].x = (_Float16)r0.z; h[2].y = (_Float16)r1.z;
    h[3].x = (_Float16)r0.w; h[3].y = (_Float16)r1.w;
    pack[lin] = *(uint4*)h;
}

// ---------------- main scan kernel (fp16 weights, register double-buffer) ----
__global__ __launch_bounds__(NTHREADS, 2)
void lstm_scan_fp16_kernel(const float* __restrict__ X,
                           const int* __restrict__ lengths,
                           const float* __restrict__ W_lin,
                           const float* __restrict__ b_lin,
                           const float* __restrict__ W_dec,
                           const float* __restrict__ b_dec,
                           const float* __restrict__ W_out,
                           const float* __restrict__ b_out,
                           const uint4* __restrict__ pack,
                           float* __restrict__ out)
{
    __shared__ float s_feats[FEATS];          // [0,H)=c_t, [H,..)=h_t row-major
    __shared__ half2_t s_inp2[H / 2];         // decayed hidden row, fp16 pairs
    __shared__ float s_part[4][H4];           // K-split matvec partials
    __shared__ float s_X[4 * T];
    __shared__ float s_wdec[NF];
    __shared__ float s_bdec[NF];
    __shared__ float s_red[16];

    float* s_ct = s_feats;
    float* s_ht = s_feats + H;

    const int tid = threadIdx.x;
    const int b   = blockIdx.x;
    const int g4  = tid & 127;
    const int kq  = tid >> 7;

    const float* Xb = X + b * 4 * T;
    const int len = lengths[b];

    for (int i = tid; i < NF * H; i += NTHREADS) s_ht[i] = 0.0f;
    for (int i = tid; i < 4 * T; i += NTHREADS) s_X[i] = Xb[i];
    if (tid < NF) { s_wdec[tid] = W_dec[tid]; s_bdec[tid] = b_dec[tid]; }
    if (tid < H / 2) { half2_t z; z.x = (_Float16)0.0f; z.y = (_Float16)0.0f; s_inp2[tid] = z; }
    __syncthreads();

    float c_t = 0.0f, acc = 0.0f, cnt = 0.0f;

    uint4 bufA[16], bufB[16];
    // prologue prefetch for step 0
    {
        const int m0 = (int)s_X[T];
        const uint4* Wp = pack + m0 * PACK_UINT4_PER_F + tid;
        #pragma unroll
        for (int i = 0; i < 16; ++i) bufA[i] = Wp[i * 512];
    }

    #define STEP(CUR, NXT)                                                          \
    {                                                                               \
        const int   mj = (int)s_X[T + j];                                           \
        const float xj = s_X[2 * T + j];                                            \
        const int   jn = (j + 1 < T) ? (j + 1) : (T - 1);                           \
        const int   mjn = (int)s_X[T + jn];                                         \
        /* prefetch next step's weights */                                          \
        {                                                                           \
            const uint4* Wp = pack + mjn * PACK_UINT4_PER_F + tid;                  \
            _Pragma("unroll")                                                       \
            for (int i = 0; i < 16; ++i) NXT[i] = Wp[i * 512];                      \
        }                                                                           \
        /* bias prefetch for current step (consumed after barrier) */               \
        float bl0, bl1, bl2, bl3;                                                   \
        if (tid < H) {                                                              \
            const int m4 = mj * H4;                                                 \
            bl0 = b_lin[m4 + tid];                                                  \
            bl1 = b_lin[m4 + H + tid];                                              \
            bl2 = b_lin[m4 + 2 * H + tid];                                          \
            bl3 = b_lin[m4 + 3 * H + tid];                                          \
        }                                                                           \
        /* matvec over preloaded registers */                                       \
        float a0 = 0.0f, a1 = 0.0f, a2 = 0.0f, a3 = 0.0f;                           \
        _Pragma("unroll")                                                           \
        for (int i = 0; i < 16; ++i) {                                              \
            union { uint4 u; half2_t h[4]; } cv;                                    \
            cv.u = CUR[i];                                                          \
            const half2_t iv = s_inp2[kq * 16 + i];                                 \
            a0 = fdot2_(cv.h[0], iv, a0);                                           \
            a1 = fdot2_(cv.h[1], iv, a1);                                           \
            a2 = fdot2_(cv.h[2], iv, a2);                                           \
            a3 = fdot2_(cv.h[3], iv, a3);                                           \
        }                                                                           \
        if (kq == 0) {  /* x-term: fp32 row 0 of W_lin[mj] */                       \
            const float4 w = *(const float4*)(W_lin + (size_t)mj * WF_STRIDE + 4 * g4); \
            a0 = fmaf(xj, w.x, a0); a1 = fmaf(xj, w.y, a1);                         \
            a2 = fmaf(xj, w.z, a2); a3 = fmaf(xj, w.w, a3);                         \
        }                                                                           \
        float4 a4; a4.x = a0; a4.y = a1; a4.z = a2; a4.w = a3;                      \
        *(float4*)(&s_part[kq][4 * g4]) = a4;                                       \
        __syncthreads();  /* B: partials ready */                                   \
        if (tid < H) {                                                              \
            const int h = tid;                                                      \
            const float gi = s_part[0][h]         + s_part[1][h]         + s_part[2][h]         + s_part[3][h]         + bl0; \
            const float gf = s_part[0][H + h]     + s_part[1][H + h]     + s_part[2][H + h]     + s_part[3][H + h]     + bl1; \
            const float go = s_part[0][2*H + h]   + s_part[1][2*H + h]   + s_part[2][2*H + h]   + s_part[3][2*H + h]   + bl2; \
            const float gc = s_part[0][3*H + h]   + s_part[1][3*H + h]   + s_part[2][3*H + h]   + s_part[3][3*H + h]   + bl3; \
            const float c_cand = sigmoidf_(gf) * c_t + sigmoidf_(gi) * tanhf_(gc);  \
            const float h_row  = sigmoidf_(go) * tanhf_(c_cand);                    \
            s_ht[mj * H + h] = h_row;                                               \
            acc += c_cand;                                                          \
            cnt += 1.0f;                                                            \
            const float tj = s_X[j];                                                \
            const float tn = (j < T - 1) ? s_X[j + 1] : (tj + 1.0f);                \
            const bool boundary = (j == len - 1) || (tn != tj);                     \
            if (boundary) { c_t = acc / fmaxf(cnt, 1.0f); acc = 0.0f; cnt = 0.0f; } \
            /* produce next step's decayed input (fp16) */                          \
            const float dn  = s_X[3 * T + jn];                                      \
            const float dmn = fmaf(s_wdec[mjn], dn, s_bdec[mjn]);                   \
            const float den = __expf(-fmaxf(0.0f, dmn));                            \
            const float hv  = (mjn == mj) ? h_row : s_ht[mjn * H + h];              \
            ((_Float16*)s_inp2)[h] = (_Float16)(den * hv);                          \
        }                                                                           \
        __syncthreads();  /* A: s_inp2 + h_t ready */                               \
    }

    int j = 0;
    while (j < len) {
        STEP(bufA, bufB); ++j;
        if (j >= len) break;
        STEP(bufB, bufA); ++j;
    }
    #undef STEP

    // ---- epilogue ----
    if (tid < H) s_ct[tid] = c_t;
    __syncthreads();

    float z0 = 0.0f, z1 = 0.0f;
    for (int i = tid; i < FEATS; i += NTHREADS) {
        const float f = s_feats[i];
        const float2 w = *(const float2*)(W_out + 2 * i);
        z0 = fmaf(f, w.x, z0);
        z1 = fmaf(f, w.y, z1);
    }
    #pragma unroll
    for (int off = 32; off > 0; off >>= 1) {
        z0 += __shfl_down(z0, off, 64);
        z1 += __shfl_down(z1, off, 64);
    }
    const int wave = tid >> 6, lane = tid & 63;
    if (lane == 0) { s_red[2 * wave] = z0; s_red[2 * wave + 1] = z1; }
    __syncthreads();
    if (tid == 0) {
        float a0 = b_out[0], a1 = b_out[1];
        #pragma unroll
        for (int w = 0; w < 8; ++w) { a0 += s_red[2 * w]; a1 += s_red[2 * w + 1]; }
        const float mx = fmaxf(a0, a1);
        const float e0 = __expf(a0 - mx), e1 = __expf(a1 - mx);
        const float inv = 1.0f / (e0 + e1);
        out[2 * b]     = e0 * inv;
        out[2 * b + 1] = e1 * inv;
    }
}

// ---------------- fp32 fallback (previous round's kernel) ----------------
__global__ __launch_bounds__(NTHREADS)
void lstm_scan_kernel(const float* __restrict__ X,
                      const int* __restrict__ lengths,
                      const float* __restrict__ W_lin,
                      const float* __restrict__ b_lin,
                      const float* __restrict__ W_dec,
                      const float* __restrict__ b_dec,
                      const float* __restrict__ W_out,
                      const float* __restrict__ b_out,
                      float* __restrict__ out)
{
    __shared__ float s_feats[FEATS];
    __shared__ float s_inp[H];
    __shared__ float s_part[4][H4];
    __shared__ float s_X[4 * T];
    __shared__ float s_wdec[NF];
    __shared__ float s_bdec[NF];
    __shared__ float s_red[16];

    float* s_ct = s_feats;
    float* s_ht = s_feats + H;

    const int tid = threadIdx.x;
    const int b   = blockIdx.x;
    const int g4  = tid & 127;
    const int kq  = tid >> 7;

    const float* Xb = X + b * 4 * T;
    const int len = lengths[b];

    for (int i = tid; i < NF * H; i += NTHREADS) s_ht[i] = 0.0f;
    for (int i = tid; i < 4 * T; i += NTHREADS) s_X[i] = Xb[i];
    if (tid < NF) { s_wdec[tid] = W_dec[tid]; s_bdec[tid] = b_dec[tid]; }
    __syncthreads();

    float c_t = 0.0f, acc = 0.0f, cnt = 0.0f;

    for (int j = 0; j < len; ++j) {
        const int   mj = (int)s_X[T + j];
        const float xj = s_X[2 * T + j];
        const float* Wf = W_lin + mj * WF_STRIDE;

        float bl0, bl1, bl2, bl3;
        if (tid < H) {
            const float dj    = s_X[3 * T + j];
            const float dm    = fmaf(s_wdec[mj], dj, s_bdec[mj]);
            const float decay = __expf(-fmaxf(0.0f, dm));
            s_inp[tid] = decay * s_ht[mj * H + tid];
            const int m4 = mj * H4;
            bl0 = b_lin[m4 + tid];
            bl1 = b_lin[m4 + H + tid];
            bl2 = b_lin[m4 + 2 * H + tid];
            bl3 = b_lin[m4 + 3 * H + tid];
        }
        __syncthreads();

        float4 a4 = make_float4(0.0f, 0.0f, 0.0f, 0.0f);
        {
            const float*  wr  = Wf + (1 + kq * 32) * H4 + 4 * g4;
            const float4* ivp = (const float4*)(s_inp + kq * 32);
            #pragma unroll
            for (int c = 0; c < 8; ++c) {
                const float4 v = ivp[c];
                const float* wrc = wr + (4 * c) * H4;
                const float4 w0 = *(const float4*)(wrc);
                const float4 w1 = *(const float4*)(wrc + H4);
                const float4 w2 = *(const float4*)(wrc + 2 * H4);
                const float4 w3 = *(const float4*)(wrc + 3 * H4);
                a4.x = fmaf(v.x, w0.x, a4.x); a4.y = fmaf(v.x, w0.y, a4.y);
                a4.z = fmaf(v.x, w0.z, a4.z); a4.w = fmaf(v.x, w0.w, a4.w);
                a4.x = fmaf(v.y, w1.x, a4.x); a4.y = fmaf(v.y, w1.y, a4.y);
                a4.z = fmaf(v.y, w1.z, a4.z); a4.w = fmaf(v.y, w1.w, a4.w);
                a4.x = fmaf(v.z, w2.x, a4.x); a4.y = fmaf(v.z, w2.y, a4.y);
                a4.z = fmaf(v.z, w2.z, a4.z); a4.w = fmaf(v.z, w2.w, a4.w);
                a4.x = fmaf(v.w, w3.x, a4.x); a4.y = fmaf(v.w, w3.y, a4.y);
                a4.z = fmaf(v.w, w3.z, a4.z); a4.w = fmaf(v.w, w3.w, a4.w);
            }
        }
        if (kq == 0) {
            const float4 w = *(const float4*)(Wf + 4 * g4);
            a4.x = fmaf(xj, w.x, a4.x); a4.y = fmaf(xj, w.y, a4.y);
            a4.z = fmaf(xj, w.z, a4.z); a4.w = fmaf(xj, w.w, a4.w);
        }
        *(float4*)(&s_part[kq][4 * g4]) = a4;
        __syncthreads();

        if (tid < H) {
            const int h = tid;
            const float gi = s_part[0][h]         + s_part[1][h]         + s_part[2][h]         + s_part[3][h]         + bl0;
            const float gf = s_part[0][H + h]     + s_part[1][H + h]     + s_part[2][H + h]     + s_part[3][H + h]     + bl1;
            const float go = s_part[0][2*H + h]   + s_part[1][2*H + h]   + s_part[2][2*H + h]   + s_part[3][2*H + h]   + bl2;
            const float gc = s_part[0][3*H + h]   + s_part[1][3*H + h]   + s_part[2][3*H + h]   + s_part[3][3*H + h]   + bl3;

            const float c_cand = sigmoidf_(gf) * c_t + sigmoidf_(gi) * tanhf_(gc);
            const float h_row  = sigmoidf_(go) * tanhf_(c_cand);
            s_ht[mj * H + h] = h_row;
            acc += c_cand;
            cnt += 1.0f;

            const float tj = s_X[j];
            const float tn = (j < T - 1) ? s_X[j + 1] : (tj + 1.0f);
            const bool boundary = (j == len - 1) || (tn != tj);
            if (boundary) { c_t = acc / fmaxf(cnt, 1.0f); acc = 0.0f; cnt = 0.0f; }
        }
        __syncthreads();
    }

    if (tid < H) s_ct[tid] = c_t;
    __syncthreads();

    float z0 = 0.0f, z1 = 0.0f;
    for (int i = tid; i < FEATS; i += NTHREADS) {
        const float f = s_feats[i];
        const float2 w = *(const float2*)(W_out + 2 * i);
        z0 = fmaf(f, w.x, z0);
        z1 = fmaf(f, w.y, z1);
    }
    #pragma unroll
    for (int off = 32; off > 0; off >>= 1) {
        z0 += __shfl_down(z0, off, 64);
        z1 += __shfl_down(z1, off, 64);
    }
    const int wave = tid >> 6, lane = tid & 63;
    if (lane == 0) { s_red[2 * wave] = z0; s_red[2 * wave + 1] = z1; }
    __syncthreads();
    if (tid == 0) {
        float a0 = b_out[0], a1 = b_out[1];
        #pragma unroll
        for (int w = 0; w < 8; ++w) { a0 += s_red[2 * w]; a1 += s_red[2 * w + 1]; }
        const float mx = fmaxf(a0, a1);
        const float e0 = __expf(a0 - mx), e1 = __expf(a1 - mx);
        const float inv = 1.0f / (e0 + e1);
        out[2 * b]     = e0 * inv;
        out[2 * b + 1] = e1 * inv;
    }
}

extern "C" void kernel_launch(void* const* d_in, const int* in_sizes, int n_in,
                              void* d_out, int out_size, void* d_ws, size_t ws_size,
                              hipStream_t stream) {
    const float* X      = (const float*)d_in[0];
    const int*   lens   = (const int*)d_in[1];
    const float* W_lin  = (const float*)d_in[2];
    const float* b_lin  = (const float*)d_in[3];
    const float* W_dec  = (const float*)d_in[4];
    const float* b_dec  = (const float*)d_in[5];
    const float* W_out  = (const float*)d_in[6];
    const float* b_out  = (const float*)d_in[7];
    float* out = (float*)d_out;

    if (ws_size >= (size_t)PACK_BYTES) {
        uint4* pack = (uint4*)d_ws;
        hipLaunchKernelGGL(repack_kernel, dim3(2048), dim3(256), 0, stream, W_lin, pack);
        hipLaunchKernelGGL(lstm_scan_fp16_kernel, dim3(BATCH), dim3(NTHREADS), 0, stream,
                           X, lens, W_lin, b_lin, W_dec, b_dec, W_out, b_out, pack, out);
    } else {
        hipLaunchKernelGGL(lstm_scan_kernel, dim3(BATCH), dim3(NTHREADS), 0, stream,
                           X, lens, W_lin, b_lin, W_dec, b_dec, W_out, b_out, out);
    }
}